// Round 2
// baseline (2031.019 us; speedup 1.0000x reference)
//
#include <hip/hip_runtime.h>

#define LRELU(x) ((x) >= 0.0f ? (x) : 0.2f * (x))

typedef __attribute__((ext_vector_type(8))) short short8;
typedef __attribute__((ext_vector_type(4))) float f32x4;

__device__ __forceinline__ unsigned short f2bf(float f) {
    union { float f; unsigned int u; } v; v.f = f;
    unsigned int u = v.u;
    u += 0x7FFFu + ((u >> 16) & 1u);   // round-to-nearest-even
    return (unsigned short)(u >> 16);
}

__device__ __forceinline__ float bf2f(unsigned short u) {
    union { unsigned int u; float f; } v; v.u = ((unsigned int)u) << 16;
    return v.f;
}

// ---------------------------------------------------------------------------
// K1: node attention tables: fc = feat@W_prop, as = feat@W_attn_src,
//     ad = feat@W_attn_dst   (each [N,8])
// ---------------------------------------------------------------------------
__global__ __launch_bounds__(256) void k_node_tables(
    const float* __restrict__ feat,
    const float* __restrict__ Wp, const float* __restrict__ Was,
    const float* __restrict__ Wad,
    float* __restrict__ fc, float* __restrict__ as_t, float* __restrict__ ad_t,
    int N)
{
    __shared__ float Wl[3 * 2048];  // 3 x [256][8]
    for (int i = threadIdx.x; i < 3 * 2048; i += 256) {
        float v;
        if (i < 2048)      v = Wp[i];
        else if (i < 4096) v = Was[i - 2048];
        else               v = Wad[i - 4096];
        Wl[i] = v;
    }
    __syncthreads();
    int gid = blockIdx.x * 256 + threadIdx.x;
    int n = gid >> 3, h = gid & 7;
    if (n >= N) return;
    const float4* f4 = (const float4*)(feat + (size_t)n * 256);
    float aP = 0.f, aS = 0.f, aD = 0.f;
#pragma unroll 8
    for (int k4 = 0; k4 < 64; ++k4) {
        float4 f = f4[k4];
        int b = k4 * 32 + h;
        aP += f.x * Wl[b]        + f.y * Wl[b + 8]        + f.z * Wl[b + 16]        + f.w * Wl[b + 24];
        aS += f.x * Wl[2048 + b] + f.y * Wl[2048 + b + 8] + f.z * Wl[2048 + b + 16] + f.w * Wl[2048 + b + 24];
        aD += f.x * Wl[4096 + b] + f.y * Wl[4096 + b + 8] + f.z * Wl[4096 + b + 16] + f.w * Wl[4096 + b + 24];
    }
    fc[gid] = aP; as_t[gid] = aS; ad_t[gid] = aD;
}

// ---------------------------------------------------------------------------
// Shared edge-attention compute
// ---------------------------------------------------------------------------
__device__ __forceinline__ float edge_ex(
    const float* __restrict__ feat_edge, const float* Wl,
    const float* __restrict__ as_t, const float* __restrict__ ad_t,
    int e, int h, int s, int d)
{
    const float4* fe = (const float4*)(feat_edge + (size_t)e * 16);
    float4 f0 = fe[0], f1 = fe[1], f2 = fe[2], f3 = fe[3];
    float ae = f0.x * Wl[h]      + f0.y * Wl[h + 8]   + f0.z * Wl[h + 16]  + f0.w * Wl[h + 24]
             + f1.x * Wl[h + 32] + f1.y * Wl[h + 40]  + f1.z * Wl[h + 48]  + f1.w * Wl[h + 56]
             + f2.x * Wl[h + 64] + f2.y * Wl[h + 72]  + f2.z * Wl[h + 80]  + f2.w * Wl[h + 88]
             + f3.x * Wl[h + 96] + f3.y * Wl[h + 104] + f3.z * Wl[h + 112] + f3.w * Wl[h + 120];
    float ev = as_t[s * 8 + h] + ad_t[d * 8 + h] + ae;
    ev = LRELU(ev);
    return __expf(ev);
}

// ======================= CSR (atomic-free) path ============================
__global__ __launch_bounds__(256) void k_hist(
    const int* __restrict__ src, const int* __restrict__ dst,
    int* __restrict__ cnt, int N, int E)
{
    int e = blockIdx.x * 256 + threadIdx.x;
    if (e >= E) return;
    atomicAdd(&cnt[dst[e]], 1);
    atomicAdd(&cnt[N + src[e]], 1);
}

__global__ __launch_bounds__(1024) void k_scan(
    const int* __restrict__ cnt, int* __restrict__ off,
    int* __restrict__ cur, int len)
{
    __shared__ int part[1024];
    int t = threadIdx.x;
    int C = (len + 1023) >> 10;
    int b = t * C;
    int e = b + C; if (e > len) e = len;
    int s = 0;
    for (int k = b; k < e; ++k) s += cnt[k];
    part[t] = s;
    __syncthreads();
    for (int o = 1; o < 1024; o <<= 1) {
        int v = (t >= o) ? part[t - o] : 0;
        __syncthreads();
        part[t] += v;
        __syncthreads();
    }
    int run = (t == 0) ? 0 : part[t - 1];
    for (int k = b; k < e; ++k) {
        int c = cnt[k];
        off[k] = run; cur[k] = run;
        run += c;
    }
    if (t == 1023) off[len] = part[1023];
}

__global__ __launch_bounds__(256) void k_scatter(
    const int* __restrict__ src, const int* __restrict__ dst,
    int* __restrict__ cur,
    int* __restrict__ ed_, int* __restrict__ sd_, int* __restrict__ dd_,
    int* __restrict__ isrc_, int N, int E)
{
    int e = blockIdx.x * 256 + threadIdx.x;
    if (e >= E) return;
    int s = src[e], d = dst[e];
    int i = atomicAdd(&cur[d], 1);          // dst-order position in [0,E)
    ed_[i] = e; sd_[i] = s; dd_[i] = d;
    int j = atomicAdd(&cur[N + s], 1);      // src-order position in [E,2E)
    isrc_[j - E] = i;
}

__global__ __launch_bounds__(256) void k_ex(
    const float* __restrict__ feat_edge, const float* __restrict__ We,
    const int* __restrict__ ed_, const int* __restrict__ sd_,
    const int* __restrict__ dd_,
    const float* __restrict__ as_t, const float* __restrict__ ad_t,
    unsigned short* __restrict__ exd, int E)
{
    __shared__ float Wl[128];
    if (threadIdx.x < 128) Wl[threadIdx.x] = We[threadIdx.x];
    __syncthreads();
    int gid = blockIdx.x * 256 + threadIdx.x;
    int i = gid >> 3, h = gid & 7;
    if (i >= E) return;
    int e = ed_[i], s = sd_[i], d = dd_[i];
    float ex = edge_ex(feat_edge, Wl, as_t, ad_t, e, h, s, d);
    exd[i * 8 + h] = f2bf(ex);
}

__global__ __launch_bounds__(256) void k_sums_src(
    const unsigned short* __restrict__ exd, const int* __restrict__ isrc_,
    const int* __restrict__ off, float* __restrict__ S_s, int N, int E)
{
    int wv = threadIdx.x >> 6;
    int s = blockIdx.x * 4 + wv;
    if (s >= N) return;
    int lane = threadIdx.x & 63, g = lane >> 3;
    int h = lane & 7;
    int jb = off[N + s] - E, je = off[N + s + 1] - E;
    float acc = 0.f;
    for (int j = jb + g; j < je; j += 8) {
        int i = isrc_[j];
        acc += bf2f(exd[i * 8 + h]);
    }
    acc += __shfl_xor(acc, 8);
    acc += __shfl_xor(acc, 16);
    acc += __shfl_xor(acc, 32);
    if (lane < 8) S_s[s * 8 + lane] = acc;
}

__global__ __launch_bounds__(256) void k_msg(
    const unsigned short* __restrict__ exd, const int* __restrict__ sd_,
    const int* __restrict__ off, const float* __restrict__ S_s,
    const float* __restrict__ fc, float* __restrict__ msg, int N)
{
    int wv = threadIdx.x >> 6;
    int d = blockIdx.x * 4 + wv;
    if (d >= N) return;
    int lane = threadIdx.x & 63, g = lane >> 3;
    int h = lane & 7;
    int db = off[d], de = off[d + 1];

    float sdsum = 0.f;
    for (int i = db + g; i < de; i += 8)
        sdsum += bf2f(exd[i * 8 + h]);
    sdsum += __shfl_xor(sdsum, 8);
    sdsum += __shfl_xor(sdsum, 16);
    sdsum += __shfl_xor(sdsum, 32);

    float acc = 0.f;
    for (int i = db + g; i < de; i += 8) {
        int s = sd_[i];
        float ex = bf2f(exd[i * 8 + h]);
        float a_d = fmaxf(ex / sdsum, 1e-9f);
        float a_s = fmaxf(ex / S_s[s * 8 + h], 1e-9f);
        acc += fc[s * 8 + h] * sqrtf(a_d * a_s);
    }
    acc += __shfl_xor(acc, 8);
    acc += __shfl_xor(acc, 16);
    acc += __shfl_xor(acc, 32);
    if (lane < 8) msg[d * 8 + lane] = acc;
}

// ======================= Fallback (atomic) path ============================
__global__ __launch_bounds__(256) void k_edge1(
    const float* __restrict__ feat_edge,
    const int* __restrict__ src, const int* __restrict__ dst,
    const float* __restrict__ We,
    const float* __restrict__ as_t, const float* __restrict__ ad_t,
    float* __restrict__ sum_dst, float* __restrict__ sum_src, int E)
{
    __shared__ float Wl[128];
    if (threadIdx.x < 128) Wl[threadIdx.x] = We[threadIdx.x];
    __syncthreads();
    int gid = blockIdx.x * 256 + threadIdx.x;
    int e = gid >> 3, h = gid & 7;
    if (e >= E) return;
    int s = src[e], d = dst[e];
    float ex = edge_ex(feat_edge, Wl, as_t, ad_t, e, h, s, d);
    atomicAdd(&sum_dst[d * 8 + h], ex);
    atomicAdd(&sum_src[s * 8 + h], ex);
}

__global__ __launch_bounds__(256) void k_edge2(
    const float* __restrict__ feat_edge,
    const int* __restrict__ src, const int* __restrict__ dst,
    const float* __restrict__ We,
    const float* __restrict__ as_t, const float* __restrict__ ad_t,
    const float* __restrict__ sum_dst, const float* __restrict__ sum_src,
    const float* __restrict__ fc, float* __restrict__ msg, int E)
{
    __shared__ float Wl[128];
    if (threadIdx.x < 128) Wl[threadIdx.x] = We[threadIdx.x];
    __syncthreads();
    int gid = blockIdx.x * 256 + threadIdx.x;
    int e = gid >> 3, h = gid & 7;
    if (e >= E) return;
    int s = src[e], d = dst[e];
    float ex = edge_ex(feat_edge, Wl, as_t, ad_t, e, h, s, d);
    float a_d = fmaxf(ex / sum_dst[d * 8 + h], 1e-9f);
    float a_s = fmaxf(ex / sum_src[s * 8 + h], 1e-9f);
    float a = sqrtf(a_d * a_s);
    atomicAdd(&msg[d * 8 + h], fc[s * 8 + h] * a);
}

// ---------------------------------------------------------------------------
// BatchNorm statistics: accum[0..7] = sum_h, accum[8..15] = sumsq_h
// ---------------------------------------------------------------------------
__global__ __launch_bounds__(256) void k_bn_stats(
    const float* __restrict__ msg, float* __restrict__ accum, int N)
{
    __shared__ float s1[8], s2[8];
    if (threadIdx.x < 8) { s1[threadIdx.x] = 0.f; s2[threadIdx.x] = 0.f; }
    __syncthreads();
    int h = threadIdx.x & 7;
    float a1 = 0.f, a2 = 0.f;
    int total = N * 8;
    for (int i = blockIdx.x * 256 + threadIdx.x; i < total; i += gridDim.x * 256) {
        float x = msg[i];
        a1 += x; a2 += x * x;
    }
    atomicAdd(&s1[h], a1);
    atomicAdd(&s2[h], a2);
    __syncthreads();
    if (threadIdx.x < 8) {
        atomicAdd(&accum[threadIdx.x], s1[threadIdx.x]);
        atomicAdd(&accum[8 + threadIdx.x], s2[threadIdx.x]);
    }
}

// ---------------------------------------------------------------------------
// Prep: bf16 weight tables in B-fragment layout [chunk][n:256][k:32]
// ---------------------------------------------------------------------------
__global__ __launch_bounds__(256) void k_prep(
    const float* __restrict__ W1, const float* __restrict__ Wagg,
    const float* __restrict__ W2,
    const float* __restrict__ b_agg, const float* __restrict__ b1,
    const float* __restrict__ b2,
    unsigned short* __restrict__ B1t, unsigned short* __restrict__ B2t,
    float* __restrict__ bias1, float* __restrict__ bias2)
{
    int idx = blockIdx.x * 256 + threadIdx.x;
    if (idx < 73728) {                       // 9 chunks * 8192
        int c = idx >> 13, rem = idx & 8191;
        int n = rem >> 5, k = rem & 31;
        float v;
        if (c < 8) v = W1[(c * 32 + k) * 256 + n];
        else       v = (k < 8) ? Wagg[k * 256 + n] : 0.f;
        B1t[idx] = f2bf(v);
    } else if (idx < 139264) {               // + 8 chunks * 8192
        int j = idx - 73728;
        int c = j >> 13, rem = j & 8191;
        int n = rem >> 5, k = rem & 31;
        B2t[j] = f2bf(W2[(c * 32 + k) * 256 + n]);
    } else if (idx < 139520) {
        int n = idx - 139264;
        bias1[n] = b_agg[n] + b1[n];
    } else if (idx < 139776) {
        int n = idx - 139520;
        bias2[n] = b2[n];
    }
}

// ---------------------------------------------------------------------------
// Fused MFMA kernel (BN folded into h staging):
//   h   = BN(msg) * gamma + beta                [from accum stats]
//   rst = LRELU( feat@W1 + h@Wagg + bias1 )     [GEMM1, K=288 bf16 MFMA]
//   out = rst@W2 + bias2                        [GEMM2, K=256, rst in LDS]
// ---------------------------------------------------------------------------
#define ASTRIDE 296   // 288 K + 8 pad (bf16) -> 2-way (free) LDS conflicts

__global__ __launch_bounds__(256, 2) void k_fused_apply(
    const float* __restrict__ feat, const float* __restrict__ msg,
    const float* __restrict__ accum,
    const float* __restrict__ gamma, const float* __restrict__ beta,
    const unsigned short* __restrict__ B1t,
    const unsigned short* __restrict__ B2t,
    const float* __restrict__ bias1, const float* __restrict__ bias2,
    float* __restrict__ out, int N)
{
    __shared__ __align__(16) unsigned short As[64 * ASTRIDE];
    __shared__ __align__(16) unsigned short Bs[8192];

    int tid = threadIdx.x;
    int row0 = blockIdx.x * 64;

#pragma unroll
    for (int t = 0; t < 16; ++t) {
        int i = tid + t * 256;
        int r = i >> 6, k4 = i & 63;
        float4 f = make_float4(0.f, 0.f, 0.f, 0.f);
        if (row0 + r < N)
            f = ((const float4*)(feat + (size_t)(row0 + r) * 256))[k4];
        ushort4 b;
        b.x = f2bf(f.x); b.y = f2bf(f.y); b.z = f2bf(f.z); b.w = f2bf(f.w);
        *(ushort4*)&As[r * ASTRIDE + k4 * 4] = b;
    }
    // h staging with BN applied on the fly
#pragma unroll
    for (int t = 0; t < 8; ++t) {
        int e = tid + t * 256;
        int r = e >> 5, c = e & 31;
        float v = 0.f;
        if (c < 8 && row0 + r < N) {
            float invN = 1.0f / (float)N;
            float mu = accum[c] * invN;
            float var = accum[8 + c] * invN - mu * mu;
            float rstd = rsqrtf(var + 1e-5f);
            v = (msg[(size_t)(row0 + r) * 8 + c] - mu) * rstd * gamma[c] + beta[c];
        }
        As[r * ASTRIDE + 256 + c] = f2bf(v);
    }

    int wave = tid >> 6;
    int lane = tid & 63;
    int n16  = lane & 15;
    int quad = lane >> 4;
    int col0 = wave * 64;

    f32x4 acc[4][4];
#pragma unroll
    for (int rt = 0; rt < 4; ++rt)
#pragma unroll
        for (int ct = 0; ct < 4; ++ct)
            acc[rt][ct] = (f32x4){0.f, 0.f, 0.f, 0.f};

    for (int kc = 0; kc < 9; ++kc) {
        __syncthreads();
#pragma unroll
        for (int t = 0; t < 4; ++t) {
            int i = tid + t * 256;
            ((float4*)Bs)[i] = ((const float4*)(B1t + kc * 8192))[i];
        }
        __syncthreads();
        int kbase = kc * 32;
        short8 af[4], bf[4];
#pragma unroll
        for (int rt = 0; rt < 4; ++rt)
            af[rt] = *(const short8*)&As[(rt * 16 + n16) * ASTRIDE + kbase + quad * 8];
#pragma unroll
        for (int ct = 0; ct < 4; ++ct)
            bf[ct] = *(const short8*)&Bs[(col0 + ct * 16 + n16) * 32 + quad * 8];
#pragma unroll
        for (int rt = 0; rt < 4; ++rt)
#pragma unroll
            for (int ct = 0; ct < 4; ++ct)
                acc[rt][ct] = __builtin_amdgcn_mfma_f32_16x16x32_bf16(
                    af[rt], bf[ct], acc[rt][ct], 0, 0, 0);
    }

    float bi[4];
#pragma unroll
    for (int ct = 0; ct < 4; ++ct) bi[ct] = bias1[col0 + ct * 16 + n16];
    __syncthreads();
#pragma unroll
    for (int rt = 0; rt < 4; ++rt)
#pragma unroll
        for (int ct = 0; ct < 4; ++ct)
#pragma unroll
            for (int r = 0; r < 4; ++r) {
                float v = acc[rt][ct][r] + bi[ct];
                v = LRELU(v);
                int row = rt * 16 + quad * 4 + r;
                int col = col0 + ct * 16 + n16;
                As[row * ASTRIDE + col] = f2bf(v);
            }

#pragma unroll
    for (int rt = 0; rt < 4; ++rt)
#pragma unroll
        for (int ct = 0; ct < 4; ++ct)
            acc[rt][ct] = (f32x4){0.f, 0.f, 0.f, 0.f};

    for (int kc = 0; kc < 8; ++kc) {
        __syncthreads();
#pragma unroll
        for (int t = 0; t < 4; ++t) {
            int i = tid + t * 256;
            ((float4*)Bs)[i] = ((const float4*)(B2t + kc * 8192))[i];
        }
        __syncthreads();
        int kbase = kc * 32;
        short8 af[4], bf[4];
#pragma unroll
        for (int rt = 0; rt < 4; ++rt)
            af[rt] = *(const short8*)&As[(rt * 16 + n16) * ASTRIDE + kbase + quad * 8];
#pragma unroll
        for (int ct = 0; ct < 4; ++ct)
            bf[ct] = *(const short8*)&Bs[(col0 + ct * 16 + n16) * 32 + quad * 8];
#pragma unroll
        for (int rt = 0; rt < 4; ++rt)
#pragma unroll
            for (int ct = 0; ct < 4; ++ct)
                acc[rt][ct] = __builtin_amdgcn_mfma_f32_16x16x32_bf16(
                    af[rt], bf[ct], acc[rt][ct], 0, 0, 0);
    }

    float bi2[4];
#pragma unroll
    for (int ct = 0; ct < 4; ++ct) bi2[ct] = bias2[col0 + ct * 16 + n16];
#pragma unroll
    for (int rt = 0; rt < 4; ++rt)
#pragma unroll
        for (int r = 0; r < 4; ++r) {
            int row = row0 + rt * 16 + quad * 4 + r;
            if (row < N) {
#pragma unroll
                for (int ct = 0; ct < 4; ++ct) {
                    int col = col0 + ct * 16 + n16;
                    out[(size_t)row * 256 + col] = acc[rt][ct][r] + bi2[ct];
                }
            }
        }
}

// ---------------------------------------------------------------------------
extern "C" void kernel_launch(void* const* d_in, const int* in_sizes, int n_in,
                              void* d_out, int out_size, void* d_ws, size_t ws_size,
                              hipStream_t stream)
{
    const float* feat      = (const float*)d_in[0];
    const float* feat_edge = (const float*)d_in[1];
    const int*   src       = (const int*)d_in[2];
    const int*   dst       = (const int*)d_in[3];
    const float* W_prop    = (const float*)d_in[4];
    const float* W_as      = (const float*)d_in[5];
    const float* W_ad      = (const float*)d_in[6];
    const float* W_edge    = (const float*)d_in[7];
    const float* bn_gamma  = (const float*)d_in[8];
    const float* bn_beta   = (const float*)d_in[9];
    const float* W_agg     = (const float*)d_in[10];
    const float* b_agg     = (const float*)d_in[11];
    const float* W1        = (const float*)d_in[12];
    const float* b1        = (const float*)d_in[13];
    const float* W2        = (const float*)d_in[14];
    const float* b2        = (const float*)d_in[15];
    float* out = (float*)d_out;

    int N = in_sizes[0] / 256;
    int E = in_sizes[2];
    int N8 = N * 8;

    int gridN8    = (N8 + 255) / 256;
    int gridE     = (E + 255) / 256;
    int gridE8    = (E * 8 + 255) / 256;
    int gridNode4 = (N + 3) / 4;
    int gridF     = (N + 63) / 64;

    // ---- CSR-path workspace layout (64B-aligned regions) ----
    char* base = (char*)d_ws;
    size_t o = 0;
    auto take = [&](size_t bytes) -> char* {
        char* p = base + o;
        o = (o + bytes + 63) & ~(size_t)63;
        return p;
    };
    int*   cnt   = (int*)  take((size_t)2 * N * sizeof(int));       // offset 0
    float* accum = (float*)take(16 * sizeof(float));                // right after cnt
    int*   off   = (int*)  take((size_t)(2 * N + 1) * sizeof(int));
    int*   cur   = (int*)  take((size_t)2 * N * sizeof(int));
    float* S_s   = (float*)take((size_t)N8 * sizeof(float));
    float* msg   = (float*)take((size_t)N8 * sizeof(float));
    float* fc    = (float*)take((size_t)N8 * sizeof(float));
    float* as_t  = (float*)take((size_t)N8 * sizeof(float));
    float* ad_t  = (float*)take((size_t)N8 * sizeof(float));
    float* bias1 = (float*)take(256 * sizeof(float));
    float* bias2 = (float*)take(256 * sizeof(float));
    unsigned short* B1t = (unsigned short*)take(73728 * sizeof(unsigned short));
    unsigned short* B2t = (unsigned short*)take(65536 * sizeof(unsigned short));
    int*   ed_   = (int*)  take((size_t)E * sizeof(int));
    int*   sd_   = (int*)  take((size_t)E * sizeof(int));
    int*   dd_   = (int*)  take((size_t)E * sizeof(int));
    int*   isrc_ = (int*)  take((size_t)E * sizeof(int));
    unsigned short* exd = (unsigned short*)take((size_t)E * 8 * sizeof(unsigned short));
    size_t need_csr = o;

    if (ws_size >= need_csr) {
        // =================== CSR (atomic-free) path ===================
        hipMemsetAsync(d_ws, 0, (size_t)2 * N * sizeof(int) + 64, stream);  // cnt + accum
        k_prep<<<546, 256, 0, stream>>>(W1, W_agg, W2, b_agg, b1, b2,
                                        B1t, B2t, bias1, bias2);
        k_node_tables<<<gridN8, 256, 0, stream>>>(feat, W_prop, W_as, W_ad,
                                                  fc, as_t, ad_t, N);
        k_hist<<<gridE, 256, 0, stream>>>(src, dst, cnt, N, E);
        k_scan<<<1, 1024, 0, stream>>>(cnt, off, cur, 2 * N);
        k_scatter<<<gridE, 256, 0, stream>>>(src, dst, cur, ed_, sd_, dd_, isrc_, N, E);
        k_ex<<<gridE8, 256, 0, stream>>>(feat_edge, W_edge, ed_, sd_, dd_,
                                         as_t, ad_t, exd, E);
        k_sums_src<<<gridNode4, 256, 0, stream>>>(exd, isrc_, off, S_s, N, E);
        k_msg<<<gridNode4, 256, 0, stream>>>(exd, sd_, off, S_s, fc, msg, N);
        k_bn_stats<<<512, 256, 0, stream>>>(msg, accum, N);
        k_fused_apply<<<gridF, 256, 0, stream>>>(feat, msg, accum, bn_gamma, bn_beta,
                                                 B1t, B2t, bias1, bias2, out, N);
    } else {
        // =================== Fallback (atomic) path ===================
        // layout: [sum_dst N8][sum_src N8][msg N8][accum 16][fc][as][ad][bias1][bias2][B1t][B2t]
        float* ws       = (float*)d_ws;
        float* sum_dst  = ws;
        float* sum_src  = sum_dst + N8;
        float* msgF     = sum_src + N8;
        float* accumF   = msgF + N8;
        float* fcF      = accumF + 16;
        float* asF      = fcF + N8;
        float* adF      = asF + N8;
        float* bias1F   = adF + N8;
        float* bias2F   = bias1F + 256;
        unsigned short* B1tF = (unsigned short*)(bias2F + 256);
        unsigned short* B2tF = B1tF + 73728;

        hipMemsetAsync(d_ws, 0, (size_t)(3 * N8 + 16) * sizeof(float), stream);
        k_prep<<<546, 256, 0, stream>>>(W1, W_agg, W2, b_agg, b1, b2,
                                        B1tF, B2tF, bias1F, bias2F);
        k_node_tables<<<gridN8, 256, 0, stream>>>(feat, W_prop, W_as, W_ad,
                                                  fcF, asF, adF, N);
        k_edge1<<<gridE8, 256, 0, stream>>>(feat_edge, src, dst, W_edge,
                                            asF, adF, sum_dst, sum_src, E);
        k_edge2<<<gridE8, 256, 0, stream>>>(feat_edge, src, dst, W_edge,
                                            asF, adF, sum_dst, sum_src,
                                            fcF, msgF, E);
        k_bn_stats<<<512, 256, 0, stream>>>(msgF, accumF, N);
        k_fused_apply<<<gridF, 256, 0, stream>>>(feat, msgF, accumF, bn_gamma, bn_beta,
                                                 B1tF, B2tF, bias1F, bias2F, out, N);
    }
}

// Round 3
// 973.965 us; speedup vs baseline: 2.0853x; 2.0853x over previous
//
#include <hip/hip_runtime.h>

#define LRELU(x) ((x) >= 0.0f ? (x) : 0.2f * (x))

typedef __attribute__((ext_vector_type(8))) short short8;
typedef __attribute__((ext_vector_type(4))) float f32x4;

__device__ __forceinline__ unsigned short f2bf(float f) {
    union { float f; unsigned int u; } v; v.f = f;
    unsigned int u = v.u;
    u += 0x7FFFu + ((u >> 16) & 1u);   // round-to-nearest-even
    return (unsigned short)(u >> 16);
}

__device__ __forceinline__ float bf2f(unsigned short u) {
    union { unsigned int u; float f; } v; v.u = ((unsigned int)u) << 16;
    return v.f;
}

// packed bf16x2 atomic add (one memory-side atomic for two heads)
__device__ __forceinline__ void atomic_pk_add_bf16(unsigned short* p, unsigned int pk) {
    asm volatile("global_atomic_pk_add_bf16 %0, %1, off"
                 :: "v"(p), "v"(pk) : "memory");
}

// ---------------------------------------------------------------------------
// K1: node attention tables: fc = feat@W_prop, as = feat@W_attn_src,
//     ad = feat@W_attn_dst   (each [N,8])
// ---------------------------------------------------------------------------
__global__ __launch_bounds__(256) void k_node_tables(
    const float* __restrict__ feat,
    const float* __restrict__ Wp, const float* __restrict__ Was,
    const float* __restrict__ Wad,
    float* __restrict__ fc, float* __restrict__ as_t, float* __restrict__ ad_t,
    int N)
{
    __shared__ float Wl[3 * 2048];  // 3 x [256][8]
    for (int i = threadIdx.x; i < 3 * 2048; i += 256) {
        float v;
        if (i < 2048)      v = Wp[i];
        else if (i < 4096) v = Was[i - 2048];
        else               v = Wad[i - 4096];
        Wl[i] = v;
    }
    __syncthreads();
    int gid = blockIdx.x * 256 + threadIdx.x;
    int n = gid >> 3, h = gid & 7;
    if (n >= N) return;
    const float4* f4 = (const float4*)(feat + (size_t)n * 256);
    float aP = 0.f, aS = 0.f, aD = 0.f;
#pragma unroll 8
    for (int k4 = 0; k4 < 64; ++k4) {
        float4 f = f4[k4];
        int b = k4 * 32 + h;
        aP += f.x * Wl[b]        + f.y * Wl[b + 8]        + f.z * Wl[b + 16]        + f.w * Wl[b + 24];
        aS += f.x * Wl[2048 + b] + f.y * Wl[2048 + b + 8] + f.z * Wl[2048 + b + 16] + f.w * Wl[2048 + b + 24];
        aD += f.x * Wl[4096 + b] + f.y * Wl[4096 + b + 8] + f.z * Wl[4096 + b + 16] + f.w * Wl[4096 + b + 24];
    }
    fc[gid] = aP; as_t[gid] = aS; ad_t[gid] = aD;
}

// ---------------------------------------------------------------------------
// Edge attention value
// ---------------------------------------------------------------------------
__device__ __forceinline__ float edge_ex(
    const float* __restrict__ feat_edge, const float* Wl,
    const float* __restrict__ as_t, const float* __restrict__ ad_t,
    int e, int h, int s, int d)
{
    const float4* fe = (const float4*)(feat_edge + (size_t)e * 16);
    float4 f0 = fe[0], f1 = fe[1], f2 = fe[2], f3 = fe[3];
    float ae = f0.x * Wl[h]      + f0.y * Wl[h + 8]   + f0.z * Wl[h + 16]  + f0.w * Wl[h + 24]
             + f1.x * Wl[h + 32] + f1.y * Wl[h + 40]  + f1.z * Wl[h + 48]  + f1.w * Wl[h + 56]
             + f2.x * Wl[h + 64] + f2.y * Wl[h + 72]  + f2.z * Wl[h + 80]  + f2.w * Wl[h + 88]
             + f3.x * Wl[h + 96] + f3.y * Wl[h + 104] + f3.z * Wl[h + 112] + f3.w * Wl[h + 120];
    float ev = as_t[s * 8 + h] + ad_t[d * 8 + h] + ae;
    ev = LRELU(ev);
    return __expf(ev);
}

// ---------------------------------------------------------------------------
// Pass 1: compute ex once, cache to exd (bf16), accumulate softmax sums via
// packed-bf16 atomics (heads paired -> half the atomic ops/bytes).
// ---------------------------------------------------------------------------
__global__ __launch_bounds__(256) void k_edge1(
    const float* __restrict__ feat_edge,
    const int* __restrict__ src, const int* __restrict__ dst,
    const float* __restrict__ We,
    const float* __restrict__ as_t, const float* __restrict__ ad_t,
    unsigned short* __restrict__ sum_dst_bf,
    unsigned short* __restrict__ sum_src_bf,
    unsigned short* __restrict__ exd, int E)
{
    __shared__ float Wl[128];
    if (threadIdx.x < 128) Wl[threadIdx.x] = We[threadIdx.x];
    __syncthreads();
    int gid = blockIdx.x * 256 + threadIdx.x;
    int e = gid >> 3, h = gid & 7;
    if (e >= E) return;
    int s = src[e], d = dst[e];
    float ex = edge_ex(feat_edge, Wl, as_t, ad_t, e, h, s, d);
    unsigned short exb = f2bf(ex);
    exd[gid] = exb;
    // pair heads (h even: own ex -> low half, h+1's ex -> high half)
    float exn = __shfl_xor(ex, 1);
    if ((h & 1) == 0) {
        unsigned int pk = (unsigned int)exb | ((unsigned int)f2bf(exn) << 16);
        atomic_pk_add_bf16(sum_dst_bf + d * 8 + h, pk);
        atomic_pk_add_bf16(sum_src_bf + s * 8 + h, pk);
    }
}

// ---------------------------------------------------------------------------
// Pass 2: reload cached ex, normalize (dual softmax, geometric mean),
// accumulate messages in fp32.
// ---------------------------------------------------------------------------
__global__ __launch_bounds__(256) void k_edge2(
    const unsigned short* __restrict__ exd,
    const int* __restrict__ src, const int* __restrict__ dst,
    const unsigned short* __restrict__ sum_dst_bf,
    const unsigned short* __restrict__ sum_src_bf,
    const float* __restrict__ fc, float* __restrict__ msg, int E)
{
    int gid = blockIdx.x * 256 + threadIdx.x;
    int e = gid >> 3, h = gid & 7;
    if (e >= E) return;
    int s = src[e], d = dst[e];
    float ex = bf2f(exd[gid]);
    float Sd = bf2f(sum_dst_bf[d * 8 + h]);
    float Ss = bf2f(sum_src_bf[s * 8 + h]);
    float a_d = fmaxf(ex / Sd, 1e-9f);
    float a_s = fmaxf(ex / Ss, 1e-9f);
    atomicAdd(&msg[d * 8 + h], fc[s * 8 + h] * sqrtf(a_d * a_s));
}

// ---------------------------------------------------------------------------
// BatchNorm statistics: accum[0..7] = sum_h, accum[8..15] = sumsq_h
// ---------------------------------------------------------------------------
__global__ __launch_bounds__(256) void k_bn_stats(
    const float* __restrict__ msg, float* __restrict__ accum, int N)
{
    __shared__ float s1[8], s2[8];
    if (threadIdx.x < 8) { s1[threadIdx.x] = 0.f; s2[threadIdx.x] = 0.f; }
    __syncthreads();
    int h = threadIdx.x & 7;
    float a1 = 0.f, a2 = 0.f;
    int total = N * 8;
    for (int i = blockIdx.x * 256 + threadIdx.x; i < total; i += gridDim.x * 256) {
        float x = msg[i];
        a1 += x; a2 += x * x;
    }
    atomicAdd(&s1[h], a1);
    atomicAdd(&s2[h], a2);
    __syncthreads();
    if (threadIdx.x < 8) {
        atomicAdd(&accum[threadIdx.x], s1[threadIdx.x]);
        atomicAdd(&accum[8 + threadIdx.x], s2[threadIdx.x]);
    }
}

// ---------------------------------------------------------------------------
// Prep: bf16 weight tables in B-fragment layout [chunk][n:256][k:32]
// ---------------------------------------------------------------------------
__global__ __launch_bounds__(256) void k_prep(
    const float* __restrict__ W1, const float* __restrict__ Wagg,
    const float* __restrict__ W2,
    const float* __restrict__ b_agg, const float* __restrict__ b1,
    const float* __restrict__ b2,
    unsigned short* __restrict__ B1t, unsigned short* __restrict__ B2t,
    float* __restrict__ bias1, float* __restrict__ bias2)
{
    int idx = blockIdx.x * 256 + threadIdx.x;
    if (idx < 73728) {                       // 9 chunks * 8192
        int c = idx >> 13, rem = idx & 8191;
        int n = rem >> 5, k = rem & 31;
        float v;
        if (c < 8) v = W1[(c * 32 + k) * 256 + n];
        else       v = (k < 8) ? Wagg[k * 256 + n] : 0.f;
        B1t[idx] = f2bf(v);
    } else if (idx < 139264) {               // + 8 chunks * 8192
        int j = idx - 73728;
        int c = j >> 13, rem = j & 8191;
        int n = rem >> 5, k = rem & 31;
        B2t[j] = f2bf(W2[(c * 32 + k) * 256 + n]);
    } else if (idx < 139520) {
        int n = idx - 139264;
        bias1[n] = b_agg[n] + b1[n];
    } else if (idx < 139776) {
        int n = idx - 139520;
        bias2[n] = b2[n];
    }
}

// ---------------------------------------------------------------------------
// Fused MFMA kernel (BN folded into h staging):
//   h   = BN(msg) * gamma + beta                [from accum stats]
//   rst = LRELU( feat@W1 + h@Wagg + bias1 )     [GEMM1, K=288 bf16 MFMA]
//   out = rst@W2 + bias2                        [GEMM2, K=256, rst in LDS]
// ---------------------------------------------------------------------------
#define ASTRIDE 296   // 288 K + 8 pad (bf16) -> 2-way (free) LDS conflicts

__global__ __launch_bounds__(256, 2) void k_fused_apply(
    const float* __restrict__ feat, const float* __restrict__ msg,
    const float* __restrict__ accum,
    const float* __restrict__ gamma, const float* __restrict__ beta,
    const unsigned short* __restrict__ B1t,
    const unsigned short* __restrict__ B2t,
    const float* __restrict__ bias1, const float* __restrict__ bias2,
    float* __restrict__ out, int N)
{
    __shared__ __align__(16) unsigned short As[64 * ASTRIDE];
    __shared__ __align__(16) unsigned short Bs[8192];

    int tid = threadIdx.x;
    int row0 = blockIdx.x * 64;

#pragma unroll
    for (int t = 0; t < 16; ++t) {
        int i = tid + t * 256;
        int r = i >> 6, k4 = i & 63;
        float4 f = make_float4(0.f, 0.f, 0.f, 0.f);
        if (row0 + r < N)
            f = ((const float4*)(feat + (size_t)(row0 + r) * 256))[k4];
        ushort4 b;
        b.x = f2bf(f.x); b.y = f2bf(f.y); b.z = f2bf(f.z); b.w = f2bf(f.w);
        *(ushort4*)&As[r * ASTRIDE + k4 * 4] = b;
    }
    // h staging with BN applied on the fly
#pragma unroll
    for (int t = 0; t < 8; ++t) {
        int e = tid + t * 256;
        int r = e >> 5, c = e & 31;
        float v = 0.f;
        if (c < 8 && row0 + r < N) {
            float invN = 1.0f / (float)N;
            float mu = accum[c] * invN;
            float var = accum[8 + c] * invN - mu * mu;
            float rstd = rsqrtf(var + 1e-5f);
            v = (msg[(size_t)(row0 + r) * 8 + c] - mu) * rstd * gamma[c] + beta[c];
        }
        As[r * ASTRIDE + 256 + c] = f2bf(v);
    }

    int wave = tid >> 6;
    int lane = tid & 63;
    int n16  = lane & 15;
    int quad = lane >> 4;
    int col0 = wave * 64;

    f32x4 acc[4][4];
#pragma unroll
    for (int rt = 0; rt < 4; ++rt)
#pragma unroll
        for (int ct = 0; ct < 4; ++ct)
            acc[rt][ct] = (f32x4){0.f, 0.f, 0.f, 0.f};

    for (int kc = 0; kc < 9; ++kc) {
        __syncthreads();
#pragma unroll
        for (int t = 0; t < 4; ++t) {
            int i = tid + t * 256;
            ((float4*)Bs)[i] = ((const float4*)(B1t + kc * 8192))[i];
        }
        __syncthreads();
        int kbase = kc * 32;
        short8 af[4], bf[4];
#pragma unroll
        for (int rt = 0; rt < 4; ++rt)
            af[rt] = *(const short8*)&As[(rt * 16 + n16) * ASTRIDE + kbase + quad * 8];
#pragma unroll
        for (int ct = 0; ct < 4; ++ct)
            bf[ct] = *(const short8*)&Bs[(col0 + ct * 16 + n16) * 32 + quad * 8];
#pragma unroll
        for (int rt = 0; rt < 4; ++rt)
#pragma unroll
            for (int ct = 0; ct < 4; ++ct)
                acc[rt][ct] = __builtin_amdgcn_mfma_f32_16x16x32_bf16(
                    af[rt], bf[ct], acc[rt][ct], 0, 0, 0);
    }

    float bi[4];
#pragma unroll
    for (int ct = 0; ct < 4; ++ct) bi[ct] = bias1[col0 + ct * 16 + n16];
    __syncthreads();
#pragma unroll
    for (int rt = 0; rt < 4; ++rt)
#pragma unroll
        for (int ct = 0; ct < 4; ++ct)
#pragma unroll
            for (int r = 0; r < 4; ++r) {
                float v = acc[rt][ct][r] + bi[ct];
                v = LRELU(v);
                int row = rt * 16 + quad * 4 + r;
                int col = col0 + ct * 16 + n16;
                As[row * ASTRIDE + col] = f2bf(v);
            }

#pragma unroll
    for (int rt = 0; rt < 4; ++rt)
#pragma unroll
        for (int ct = 0; ct < 4; ++ct)
            acc[rt][ct] = (f32x4){0.f, 0.f, 0.f, 0.f};

    for (int kc = 0; kc < 8; ++kc) {
        __syncthreads();
#pragma unroll
        for (int t = 0; t < 4; ++t) {
            int i = tid + t * 256;
            ((float4*)Bs)[i] = ((const float4*)(B2t + kc * 8192))[i];
        }
        __syncthreads();
        int kbase = kc * 32;
        short8 af[4], bf[4];
#pragma unroll
        for (int rt = 0; rt < 4; ++rt)
            af[rt] = *(const short8*)&As[(rt * 16 + n16) * ASTRIDE + kbase + quad * 8];
#pragma unroll
        for (int ct = 0; ct < 4; ++ct)
            bf[ct] = *(const short8*)&Bs[(col0 + ct * 16 + n16) * 32 + quad * 8];
#pragma unroll
        for (int rt = 0; rt < 4; ++rt)
#pragma unroll
            for (int ct = 0; ct < 4; ++ct)
                acc[rt][ct] = __builtin_amdgcn_mfma_f32_16x16x32_bf16(
                    af[rt], bf[ct], acc[rt][ct], 0, 0, 0);
    }

    float bi2[4];
#pragma unroll
    for (int ct = 0; ct < 4; ++ct) bi2[ct] = bias2[col0 + ct * 16 + n16];
#pragma unroll
    for (int rt = 0; rt < 4; ++rt)
#pragma unroll
        for (int r = 0; r < 4; ++r) {
            int row = row0 + rt * 16 + quad * 4 + r;
            if (row < N) {
#pragma unroll
                for (int ct = 0; ct < 4; ++ct) {
                    int col = col0 + ct * 16 + n16;
                    out[(size_t)row * 256 + col] = acc[rt][ct][r] + bi2[ct];
                }
            }
        }
}

// ---------------------------------------------------------------------------
extern "C" void kernel_launch(void* const* d_in, const int* in_sizes, int n_in,
                              void* d_out, int out_size, void* d_ws, size_t ws_size,
                              hipStream_t stream)
{
    const float* feat      = (const float*)d_in[0];
    const float* feat_edge = (const float*)d_in[1];
    const int*   src       = (const int*)d_in[2];
    const int*   dst       = (const int*)d_in[3];
    const float* W_prop    = (const float*)d_in[4];
    const float* W_as      = (const float*)d_in[5];
    const float* W_ad      = (const float*)d_in[6];
    const float* W_edge    = (const float*)d_in[7];
    const float* bn_gamma  = (const float*)d_in[8];
    const float* bn_beta   = (const float*)d_in[9];
    const float* W_agg     = (const float*)d_in[10];
    const float* b_agg     = (const float*)d_in[11];
    const float* W1        = (const float*)d_in[12];
    const float* b1        = (const float*)d_in[13];
    const float* W2        = (const float*)d_in[14];
    const float* b2        = (const float*)d_in[15];
    float* out = (float*)d_out;

    int N = in_sizes[0] / 256;
    int E = in_sizes[2];
    int N8 = N * 8;

    // ---- workspace layout (64B-aligned regions); zeroed prefix first ----
    char* base = (char*)d_ws;
    size_t o = 0;
    auto take = [&](size_t bytes) -> char* {
        char* p = base + o;
        o = (o + bytes + 63) & ~(size_t)63;
        return p;
    };
    unsigned short* sum_dst_bf = (unsigned short*)take((size_t)N8 * 2);
    unsigned short* sum_src_bf = (unsigned short*)take((size_t)N8 * 2);
    float* msg   = (float*)take((size_t)N8 * sizeof(float));
    float* accum = (float*)take(16 * sizeof(float));
    size_t zero_bytes = o;                       // everything above needs zeroing
    float* fc    = (float*)take((size_t)N8 * sizeof(float));
    float* as_t  = (float*)take((size_t)N8 * sizeof(float));
    float* ad_t  = (float*)take((size_t)N8 * sizeof(float));
    float* bias1 = (float*)take(256 * sizeof(float));
    float* bias2 = (float*)take(256 * sizeof(float));
    unsigned short* B1t = (unsigned short*)take(73728 * sizeof(unsigned short));
    unsigned short* B2t = (unsigned short*)take(65536 * sizeof(unsigned short));
    unsigned short* exd = (unsigned short*)take((size_t)E * 8 * sizeof(unsigned short));
    (void)ws_size;

    hipMemsetAsync(d_ws, 0, zero_bytes, stream);

    int gridN8 = (N8 + 255) / 256;
    int gridE8 = (E * 8 + 255) / 256;
    int gridF  = (N + 63) / 64;

    k_prep<<<546, 256, 0, stream>>>(W1, W_agg, W2, b_agg, b1, b2,
                                    B1t, B2t, bias1, bias2);
    k_node_tables<<<gridN8, 256, 0, stream>>>(feat, W_prop, W_as, W_ad,
                                              fc, as_t, ad_t, N);
    k_edge1<<<gridE8, 256, 0, stream>>>(feat_edge, src, dst, W_edge,
                                        as_t, ad_t, sum_dst_bf, sum_src_bf,
                                        exd, E);
    k_edge2<<<gridE8, 256, 0, stream>>>(exd, src, dst, sum_dst_bf, sum_src_bf,
                                        fc, msg, E);
    k_bn_stats<<<512, 256, 0, stream>>>(msg, accum, N);
    k_fused_apply<<<gridF, 256, 0, stream>>>(feat, msg, accum, bn_gamma, bn_beta,
                                             B1t, B2t, bias1, bias2, out, N);
}